// Round 9
// baseline (347.331 us; speedup 1.0000x reference)
//
#include <hip/hip_runtime.h>
#include <hip/hip_bf16.h>
#include <math.h>

typedef __attribute__((ext_vector_type(8))) short bf16x8;
typedef __attribute__((ext_vector_type(4))) short bf16x4;
typedef __attribute__((ext_vector_type(4))) float f32x4;

#define NB 4096
#define ND 1024
#define INV_T 14.2857142857142857f   // 1/0.07

__device__ inline unsigned short f2bf(float x) {
    __hip_bfloat16 h = __float2bfloat16(x);
    return *reinterpret_cast<unsigned short*>(&h);
}
__device__ inline float bf2f(unsigned short u) {
    unsigned v = ((unsigned)u) << 16;
    return __uint_as_float(v);
}
__device__ inline void gload16(const void* g, void* l) {
    __builtin_amdgcn_global_load_lds(
        (const __attribute__((address_space(1))) void*)g,
        (__attribute__((address_space(3))) void*)l, 16, 0, 0);
}

// ---------------- kernel 0: L2-normalize rows, cast to bf16 -----------------
__global__ __launch_bounds__(256) void norm_kernel(
        const float* __restrict__ M, const float* __restrict__ P,
        __hip_bfloat16* __restrict__ Mn, __hip_bfloat16* __restrict__ Pn) {
    int row = blockIdx.x & (NB - 1);
    const float* src = (blockIdx.x < NB) ? M : P;
    __hip_bfloat16* dst = (blockIdx.x < NB) ? Mn : Pn;
    int tid = threadIdx.x;
    float4 v = ((const float4*)(src + (size_t)row * ND))[tid];
    float ss = v.x * v.x + v.y * v.y + v.z * v.z + v.w * v.w;
    for (int off = 32; off; off >>= 1) ss += __shfl_down(ss, off);
    __shared__ float red[4];
    int lane = tid & 63, w = tid >> 6;
    if (lane == 0) red[w] = ss;
    __syncthreads();
    float rn = rsqrtf(red[0] + red[1] + red[2] + red[3]);
    ushort4 o;
    o.x = f2bf(v.x * rn); o.y = f2bf(v.y * rn);
    o.z = f2bf(v.z * rn); o.w = f2bf(v.w * rn);
    *(ushort4*)((unsigned short*)dst + (size_t)row * ND + tid * 4) = o;
}

// ---------------- kernel 1: per-row mask codes ------------------------------
__global__ __launch_bounds__(256) void key_kernel(
        const int* __restrict__ labels, const int* __restrict__ sm,
        const int* __restrict__ sp, int* __restrict__ code) {
    int i = blockIdx.x * 256 + threadIdx.x;
    if (i < NB) {
        int l = labels[i];
        code[i] = (l == 0) ? 0x40000000 : (1 + l + (sm[i] << 8) + (sp[i] << 16));
    }
}

// ------- kernel 2: fused row-sum + normalized masked weight matrix (bf16) ---
__global__ __launch_bounds__(256) void rowsumw_kernel(
        const float* __restrict__ cs, const int* __restrict__ code,
        unsigned short* __restrict__ W, float* __restrict__ flag) {
    int i = blockIdx.x;
    int ci = code[i];
    int tid = threadIdx.x;
    const float4* row = (const float4*)(cs + (size_t)i * NB);
    const int4* c4 = (const int4*)code;
    float4 v[4];
    int4 cj[4];
    float s = 0.f;
#pragma unroll
    for (int k = 0; k < 4; ++k) {
        int t = tid + k * 256;
        v[k] = row[t];
        cj[k] = c4[t];
        int j = t * 4;
        if (cj[k].x == ci && j + 0 != i) s += v[k].x;
        if (cj[k].y == ci && j + 1 != i) s += v[k].y;
        if (cj[k].z == ci && j + 2 != i) s += v[k].z;
        if (cj[k].w == ci && j + 3 != i) s += v[k].w;
    }
    for (int off = 1; off < 64; off <<= 1) s += __shfl_xor(s, off);
    __shared__ float red[4];
    int lane = tid & 63, w = tid >> 6;
    if (lane == 0) red[w] = s;
    __syncthreads();
    float tot = red[0] + red[1] + red[2] + red[3];
    float inv = (tot > 0.f) ? 1.f / tot : 0.f;
#pragma unroll
    for (int k = 0; k < 4; ++k) {
        int t = tid + k * 256;
        int j = t * 4;
        ushort4 o;
        o.x = (cj[k].x == ci && j + 0 != i) ? f2bf(v[k].x * inv) : (unsigned short)0;
        o.y = (cj[k].y == ci && j + 1 != i) ? f2bf(v[k].y * inv) : (unsigned short)0;
        o.z = (cj[k].z == ci && j + 2 != i) ? f2bf(v[k].z * inv) : (unsigned short)0;
        o.w = (cj[k].w == ci && j + 3 != i) ? f2bf(v[k].w * inv) : (unsigned short)0;
        *(ushort4*)&W[(size_t)i * NB + j] = o;
    }
    if (tid == 0) flag[i] = (tot > 0.f) ? 1.f : 0.f;
}

// ---------------- kernel 3: fused 256x256 8-phase GEMM + loss epilogue ------
// 528 logical blocks (XCD-chunked): b<256 cross (supertiled 2x2 over 16x16);
// b>=256 symmetric upper-tri (Mn then Pn, 136 each).
// 512 threads = 8 waves (2x4), wave tile 128x64, acc[8][4] (128 AGPR).
// K loop: 16 tiles of BK=64, 2-tile LDS dbuf (128KB), 4 phases/tile:
//   {ds_read quadrant, issue 1 stage-unit of t+1, s_barrier, setprio, 16 MFMA}
// vmcnt(0) only at tile entry. Lean phases keep arch VGPR <= 128 (no spill).
__global__ __launch_bounds__(512, 2) void mega_gemm(
        const __hip_bfloat16* __restrict__ Mn, const __hip_bfloat16* __restrict__ Pn,
        const unsigned short* __restrict__ Wg,
        float* __restrict__ rowsum1, float* __restrict__ colsum1,
        float* __restrict__ rowsum3, float* __restrict__ rowsum4,
        float* __restrict__ dots) {
    __shared__ char smem[131072] __attribute__((aligned(16)));

    int tid = threadIdx.x;
    int lane = tid & 63, w = tid >> 6;
    int wm = w >> 2, wn = w & 3;
    int lr = lane & 15, lg = lane >> 4;

    // ---- block decode (XCD-chunked swizzle: 528 = 8 * 66, bijective) ----
    int b = (blockIdx.x & 7) * 66 + (blockIdx.x >> 3);
    int bi, bj, mode;
    const __hip_bfloat16 *A, *Bm;
    if (b < 256) {
        int st = b >> 2;                 // 2x2 supertiles for L2 locality
        int sb = b & 3;
        bi = (st >> 3) * 2 + (sb >> 1);
        bj = (st & 7) * 2 + (sb & 1);
        A = Mn; Bm = Pn; mode = 0;
    } else {
        int t = b - 256;
        int md = (t >= 136) ? 1 : 0;
        t -= md * 136;
        bi = 0;
        while (t >= 16 - bi) { t -= 16 - bi; ++bi; }
        bj = bi + t;
        A = md ? Pn : Mn; Bm = A;
        mode = 1 + md;
    }
    bool offdiag = (mode == 0) || (bi != bj);
    size_t rowBase = (size_t)bi * 256;
    size_t colBase = (size_t)bj * 256;
    float* rowTgt = (mode == 0) ? rowsum1 : ((mode == 1) ? rowsum3 : rowsum4);
    float* colTgt = (mode == 0) ? colsum1 : rowTgt;

    // ---- staging addresses: pre-swizzled source (chunk ^= row&7) ----
    int sr8 = lane >> 3;                       // row within 8-row issue
    int sch = ((lane & 7) ^ sr8) * 8;          // bf16 elems (16B chunks)
    const __hip_bfloat16* gA = A + (rowBase + w * 32 + sr8) * ND + sch;
    const __hip_bfloat16* gB = Bm + (colBase + w * 32 + sr8) * ND + sch;

    f32x4 acc[8][4] = {};

    // stage-unit u (0..3) of K-tile ti: 2 gload16/thread.
    // u>>1 selects operand (A/B); u&1 selects row-pair (c = 0,1 or 2,3).
#define STAGEU(ti, u) {                                                     \
        int k0_ = (ti) * 64;                                                \
        char* base_ = smem + ((ti) & 1) * 65536 + ((u) >> 1) * 32768;       \
        const __hip_bfloat16* gp_ = ((u) >> 1) ? gB : gA;                   \
        int c0_ = ((u) & 1) * 2;                                            \
        gload16(gp_ + (size_t)c0_ * 8 * ND + k0_,                           \
                base_ + (w * 4 + c0_) * 1024);                              \
        gload16(gp_ + (size_t)(c0_ + 1) * 8 * ND + k0_,                     \
                base_ + (w * 4 + c0_ + 1) * 1024);                          \
    }

    STAGEU(0, 0); STAGEU(0, 1); STAGEU(0, 2); STAGEU(0, 3);

    for (int t = 0; t < 16; ++t) {
        asm volatile("s_waitcnt vmcnt(0)" ::: "memory");
        __builtin_amdgcn_s_barrier();
        const __hip_bfloat16* sA = (const __hip_bfloat16*)(smem + (t & 1) * 65536);
        const __hip_bfloat16* sB = sA + 16384;
        bool more = (t < 15);
#pragma unroll
        for (int ks = 0; ks < 2; ++ks) {
            int cp = ((ks * 4 + lg) ^ (lr & 7)) * 8;
            bf16x8 bv[4];
#pragma unroll
            for (int n = 0; n < 4; ++n)
                bv[n] = *(const bf16x8*)&sB[(wn * 64 + n * 16 + lr) * 64 + cp];
#pragma unroll
            for (int mh = 0; mh < 2; ++mh) {
                bf16x8 av[4];
#pragma unroll
                for (int i = 0; i < 4; ++i)
                    av[i] = *(const bf16x8*)&sA[(wm * 128 + (mh * 4 + i) * 16 + lr) * 64 + cp];
                if (more) STAGEU(t + 1, ks * 2 + mh);
                __builtin_amdgcn_s_barrier();
                __builtin_amdgcn_s_setprio(1);
#pragma unroll
                for (int i = 0; i < 4; ++i)
#pragma unroll
                    for (int n = 0; n < 4; ++n)
                        acc[mh * 4 + i][n] = __builtin_amdgcn_mfma_f32_16x16x32_bf16(
                            av[i], bv[n], acc[mh * 4 + i][n], 0, 0, 0);
                __builtin_amdgcn_s_setprio(0);
            }
        }
    }
    __syncthreads();
#undef STAGEU

    // ---- epilogue (numerics validated R4-R6) ----
    unsigned short* wl = (unsigned short*)smem;
    float d1 = 0.f, d2 = 0.f;
    float cexp[4] = {0.f, 0.f, 0.f, 0.f};

    // d1 + rexp + cexp, two 64KB halves of W[i][j] tile (128 LDS rows x 256)
#pragma unroll
    for (int h = 0; h < 2; ++h) {
#pragma unroll
        for (int c = 0; c < 8; ++c) {
            int q = w * 8 + c;
            int sr = 2 * q + (lane >> 5);                  // LDS row 0..127
            int gchunk = (lane & 31) ^ (sr & 7);           // source pre-swizzle
            int grow = ((sr >> 6) << 7) + h * 64 + (sr & 63);
            gload16(Wg + (rowBase + grow) * (size_t)NB + colBase + gchunk * 8,
                    smem + q * 1024);
        }
        __syncthreads();
#pragma unroll
        for (int mm = 0; mm < 4; ++mm) {
            int m = h * 4 + mm;
            float rexp[4] = {0.f, 0.f, 0.f, 0.f};
#pragma unroll
            for (int n = 0; n < 4; ++n) {
                int jl = wn * 64 + n * 16 + lr;
#pragma unroll
                for (int r = 0; r < 4; ++r) {
                    int rl = wm * 64 + mm * 16 + lg * 4 + r;   // LDS row
                    float sim = acc[m][n][r] * INV_T;
                    float e = __expf(sim - INV_T);
                    rexp[r] += e;
                    cexp[n] += e;
                    int ck = (jl >> 3) ^ (rl & 7);
                    d1 += bf2f(wl[rl * 256 + ck * 8 + (jl & 7)]) * sim;
                }
            }
#pragma unroll
            for (int r = 0; r < 4; ++r) {
                float v = rexp[r];
                v += __shfl_xor(v, 1); v += __shfl_xor(v, 2);
                v += __shfl_xor(v, 4); v += __shfl_xor(v, 8);
                if (lr == 0)
                    atomicAdd(&rowTgt[rowBase + wm * 128 + m * 16 + lg * 4 + r], v);
            }
        }
        __syncthreads();
    }

    if (offdiag) {
#pragma unroll
        for (int n = 0; n < 4; ++n) {
            float v = cexp[n];
            v += __shfl_xor(v, 16); v += __shfl_xor(v, 32);
            if (lg == 0)
                atomicAdd(&colTgt[colBase + wn * 64 + n * 16 + lr], v);
        }
        // d2: W[j][i] tile in two halves by i-range: rows jl 0..255, 128 cols
#pragma unroll
        for (int h = 0; h < 2; ++h) {
#pragma unroll
            for (int c = 0; c < 8; ++c) {
                int q = w * 8 + c;
                int sr = 4 * q + (lane >> 4);              // jl row 0..255
                int gchunk = (lane & 15) ^ (sr & 7);
                gload16(Wg + (colBase + sr) * (size_t)NB + rowBase + h * 128 + gchunk * 8,
                        smem + q * 1024);
            }
            __syncthreads();
            if (wm == h) {
#pragma unroll
                for (int m = 0; m < 8; ++m) {
                    int il = m * 16 + lg * 4;
#pragma unroll
                    for (int n = 0; n < 4; ++n) {
                        int jl = wn * 64 + n * 16 + lr;
                        int ck = (il >> 3) ^ (jl & 7);
                        bf16x4 wv = *(const bf16x4*)&wl[jl * 128 + ck * 8 + (il & 7)];
#pragma unroll
                        for (int r = 0; r < 4; ++r)
                            d2 += bf2f((unsigned short)wv[r]) * (acc[m][n][r] * INV_T);
                    }
                }
            }
            __syncthreads();
        }
    }

    if (mode == 0) {
        for (int off = 32; off; off >>= 1) {
            d1 += __shfl_xor(d1, off);
            d2 += __shfl_xor(d2, off);
        }
        if (lane == 0) {
            atomicAdd(&dots[0], d1);
            atomicAdd(&dots[1], d2);
        }
    } else {
        float dtot = d1 + (offdiag ? d2 : 0.f);
        for (int off = 32; off; off >>= 1) dtot += __shfl_xor(dtot, off);
        if (lane == 0) atomicAdd(&dots[1 + mode], dtot);
    }
}

// ---------------- kernel 4: finalize --------------------------------------
__global__ __launch_bounds__(256) void finalize_kernel(
        const float* __restrict__ rowsum1, const float* __restrict__ colsum1,
        const float* __restrict__ rowsum3, const float* __restrict__ rowsum4,
        const float* __restrict__ flag, const float* __restrict__ dots,
        float* __restrict__ out) {
    int tid = threadIdx.x;
    float l = 0.f;
    for (int i = tid; i < NB; i += 256) {
        if (flag[i] != 0.f) {
            l += 4.f * INV_T + logf(rowsum1[i]) + logf(colsum1[i]) +
                 logf(rowsum3[i]) + logf(rowsum4[i]);
        }
    }
    for (int off = 32; off; off >>= 1) l += __shfl_down(l, off);
    __shared__ float red[4];
    int lane = tid & 63, w = tid >> 6;
    if (lane == 0) red[w] = l;
    __syncthreads();
    if (tid == 0) {
        float L = red[0] + red[1] + red[2] + red[3];
        float dt = dots[0] + dots[1] + dots[2] + dots[3];
        out[0] = (L - dt) / (4.0f * (float)NB);
    }
}

extern "C" void kernel_launch(void* const* d_in, const int* in_sizes, int n_in,
                              void* d_out, int out_size, void* d_ws, size_t ws_size,
                              hipStream_t stream) {
    const float* M = (const float*)d_in[0];
    const float* P = (const float*)d_in[1];
    const int* labels = (const int*)d_in[2];
    const int* sm = (const int*)d_in[3];
    const int* sp = (const int*)d_in[4];
    const float* cs = (const float*)d_in[5];
    float* out = (float*)d_out;

    char* ws = (char*)d_ws;
    __hip_bfloat16* Mn = (__hip_bfloat16*)ws;                              // 8 MB
    __hip_bfloat16* Pn = (__hip_bfloat16*)(ws + (size_t)8 * 1024 * 1024);  // 8 MB
    unsigned short* W = (unsigned short*)(ws + (size_t)16 * 1024 * 1024);  // 32 MB
    char* p = ws + (size_t)48 * 1024 * 1024;
    int* code = (int*)p;        p += 16384;
    float* flag = (float*)p;    p += 16384;
    float* rowsum1 = (float*)p; p += 16384;
    float* colsum1 = (float*)p; p += 16384;
    float* rowsum3 = (float*)p; p += 16384;
    float* rowsum4 = (float*)p; p += 16384;
    float* dots = (float*)p;

    hipMemsetAsync(rowsum1, 0, 4 * 16384 + 256, stream);

    norm_kernel<<<2 * NB, 256, 0, stream>>>(M, P, Mn, Pn);
    key_kernel<<<NB / 256, 256, 0, stream>>>(labels, sm, sp, code);
    rowsumw_kernel<<<NB, 256, 0, stream>>>(cs, code, W, flag);

    mega_gemm<<<528, 512, 0, stream>>>(Mn, Pn, W, rowsum1, colsum1,
                                       rowsum3, rowsum4, dots);

    finalize_kernel<<<1, 256, 0, stream>>>(rowsum1, colsum1, rowsum3, rowsum4,
                                           flag, dots, out);
}

// Round 10
// 267.967 us; speedup vs baseline: 1.2962x; 1.2962x over previous
//
#include <hip/hip_runtime.h>
#include <hip/hip_bf16.h>
#include <math.h>

typedef __attribute__((ext_vector_type(8))) short bf16x8;
typedef __attribute__((ext_vector_type(4))) short bf16x4;
typedef __attribute__((ext_vector_type(4))) float f32x4;

#define NB 4096
#define ND 1024
#define INV_T 14.2857142857142857f   // 1/0.07

__device__ inline unsigned short f2bf(float x) {
    __hip_bfloat16 h = __float2bfloat16(x);
    return *reinterpret_cast<unsigned short*>(&h);
}
__device__ inline float bf2f(unsigned short u) {
    unsigned v = ((unsigned)u) << 16;
    return __uint_as_float(v);
}
__device__ inline void gload16(const void* g, void* l) {
    __builtin_amdgcn_global_load_lds(
        (const __attribute__((address_space(1))) void*)g,
        (__attribute__((address_space(3))) void*)l, 16, 0, 0);
}

// ---------------- kernel 0: L2-normalize rows, cast to bf16 -----------------
__global__ __launch_bounds__(256) void norm_kernel(
        const float* __restrict__ M, const float* __restrict__ P,
        __hip_bfloat16* __restrict__ Mn, __hip_bfloat16* __restrict__ Pn) {
    int row = blockIdx.x & (NB - 1);
    const float* src = (blockIdx.x < NB) ? M : P;
    __hip_bfloat16* dst = (blockIdx.x < NB) ? Mn : Pn;
    int tid = threadIdx.x;
    float4 v = ((const float4*)(src + (size_t)row * ND))[tid];
    float ss = v.x * v.x + v.y * v.y + v.z * v.z + v.w * v.w;
    for (int off = 32; off; off >>= 1) ss += __shfl_down(ss, off);
    __shared__ float red[4];
    int lane = tid & 63, w = tid >> 6;
    if (lane == 0) red[w] = ss;
    __syncthreads();
    float rn = rsqrtf(red[0] + red[1] + red[2] + red[3]);
    ushort4 o;
    o.x = f2bf(v.x * rn); o.y = f2bf(v.y * rn);
    o.z = f2bf(v.z * rn); o.w = f2bf(v.w * rn);
    *(ushort4*)((unsigned short*)dst + (size_t)row * ND + tid * 4) = o;
}

// ---------------- kernel 1: per-row mask codes ------------------------------
__global__ __launch_bounds__(256) void key_kernel(
        const int* __restrict__ labels, const int* __restrict__ sm,
        const int* __restrict__ sp, int* __restrict__ code) {
    int i = blockIdx.x * 256 + threadIdx.x;
    if (i < NB) {
        int l = labels[i];
        code[i] = (l == 0) ? 0x40000000 : (1 + l + (sm[i] << 8) + (sp[i] << 16));
    }
}

// ------- kernel 2: fused row-sum + normalized masked weight matrix (bf16) ---
__global__ __launch_bounds__(256) void rowsumw_kernel(
        const float* __restrict__ cs, const int* __restrict__ code,
        unsigned short* __restrict__ W, float* __restrict__ flag) {
    int i = blockIdx.x;
    int ci = code[i];
    int tid = threadIdx.x;
    const float4* row = (const float4*)(cs + (size_t)i * NB);
    const int4* c4 = (const int4*)code;
    float4 v[4];
    int4 cj[4];
    float s = 0.f;
#pragma unroll
    for (int k = 0; k < 4; ++k) {
        int t = tid + k * 256;
        v[k] = row[t];
        cj[k] = c4[t];
        int j = t * 4;
        if (cj[k].x == ci && j + 0 != i) s += v[k].x;
        if (cj[k].y == ci && j + 1 != i) s += v[k].y;
        if (cj[k].z == ci && j + 2 != i) s += v[k].z;
        if (cj[k].w == ci && j + 3 != i) s += v[k].w;
    }
    for (int off = 1; off < 64; off <<= 1) s += __shfl_xor(s, off);
    __shared__ float red[4];
    int lane = tid & 63, w = tid >> 6;
    if (lane == 0) red[w] = s;
    __syncthreads();
    float tot = red[0] + red[1] + red[2] + red[3];
    float inv = (tot > 0.f) ? 1.f / tot : 0.f;
#pragma unroll
    for (int k = 0; k < 4; ++k) {
        int t = tid + k * 256;
        int j = t * 4;
        ushort4 o;
        o.x = (cj[k].x == ci && j + 0 != i) ? f2bf(v[k].x * inv) : (unsigned short)0;
        o.y = (cj[k].y == ci && j + 1 != i) ? f2bf(v[k].y * inv) : (unsigned short)0;
        o.z = (cj[k].z == ci && j + 2 != i) ? f2bf(v[k].z * inv) : (unsigned short)0;
        o.w = (cj[k].w == ci && j + 3 != i) ? f2bf(v[k].w * inv) : (unsigned short)0;
        *(ushort4*)&W[(size_t)i * NB + j] = o;
    }
    if (tid == 0) flag[i] = (tot > 0.f) ? 1.f : 0.f;
}

// ---------------- kernel 3: fused 256x128-tile GEMM + loss epilogue ---------
// 1056 logical blocks (XCD-chunked, 1056 = 8*132):
//   b < 512: cross S1 = Mn Pn^T. bi = b>>5 (0..15), bj2 = b&31 -> bj=bj2>>1,
//            ch = bj2&1. Tile rows [bi*256,+256), cols [bj*256+ch*128,+128).
//   b >= 512: symmetric (Mn then Pn), upper-tri supertiles x 2 col-halves.
// 512 threads = 8 waves (4x2), wave tile 64x64, acc[4][4] = 64 AGPR/lane
// (R8-proven no-spill envelope: ~148 arch + 64 acc < 256-reg pool).
// K loop: 16 tiles BK=64, 2 x 48KB LDS dbuf, counted vmcnt(6) depth-2.
__global__ __launch_bounds__(512) void mega_gemm(
        const __hip_bfloat16* __restrict__ Mn, const __hip_bfloat16* __restrict__ Pn,
        const unsigned short* __restrict__ Wg,
        float* __restrict__ rowsum1, float* __restrict__ colsum1,
        float* __restrict__ rowsum3, float* __restrict__ rowsum4,
        float* __restrict__ dots) {
    __shared__ char smem[98304] __attribute__((aligned(16)));

    int tid = threadIdx.x;
    int lane = tid & 63, w = tid >> 6;
    int wm = w >> 1, wn = w & 1;            // 4x2 wave grid
    int lr = lane & 15, lg = lane >> 4;

    // ---- block decode ----
    int b = (blockIdx.x & 7) * 132 + (blockIdx.x >> 3);
    int bi, bj, ch, mode;
    const __hip_bfloat16 *A, *Bm;
    if (b < 512) {
        bi = b >> 5;
        bj = (b & 31) >> 1;
        ch = b & 1;
        A = Mn; Bm = Pn; mode = 0;
    } else {
        int s = b - 512;
        int md = (s >= 272) ? 1 : 0;
        s -= md * 272;
        ch = s & 1;
        int t = s >> 1;
        bi = 0;
        while (t >= 16 - bi) { t -= 16 - bi; ++bi; }
        bj = bi + t;
        A = md ? Pn : Mn; Bm = A;
        mode = 1 + md;
    }
    bool offdiag = (mode == 0) || (bi != bj);
    size_t rowBase = (size_t)bi * 256;
    size_t colBase = (size_t)bj * 256 + ch * 128;
    float* rowTgt = (mode == 0) ? rowsum1 : ((mode == 1) ? rowsum3 : rowsum4);
    float* colTgt = (mode == 0) ? colsum1 : rowTgt;

    // ---- staging addresses: pre-swizzled source (chunk ^= row&7) ----
    int sr8 = lane >> 3;                       // row within 8-row issue
    int sch = ((lane & 7) ^ sr8) * 8;          // bf16 elems (16B chunks)
    const __hip_bfloat16* gA = A + (rowBase + w * 32 + sr8) * ND + sch;
    const __hip_bfloat16* gB = Bm + (colBase + w * 16 + sr8) * ND + sch;

    f32x4 acc[4][4] = {};

    // per tile: A 256x64 (32KB, 4 issues/thread) + B 128x64 (16KB, 2 issues)
#define STAGE(bufi, t) {                                                    \
        int k0_ = (t) * 64;                                                 \
        char* baseA_ = smem + (bufi) * 49152;                               \
        char* baseB_ = baseA_ + 32768;                                      \
        _Pragma("unroll")                                                   \
        for (int c = 0; c < 4; ++c)                                         \
            gload16(gA + (size_t)c * 8 * ND + k0_, baseA_ + (w * 4 + c) * 1024); \
        _Pragma("unroll")                                                   \
        for (int c = 0; c < 2; ++c)                                         \
            gload16(gB + (size_t)c * 8 * ND + k0_, baseB_ + (w * 2 + c) * 1024); \
    }
#define COMPUTE(bufi) {                                                     \
        const __hip_bfloat16* sA = (const __hip_bfloat16*)(smem + (bufi) * 49152); \
        const __hip_bfloat16* sB = sA + 16384;                              \
        _Pragma("unroll")                                                   \
        for (int ks = 0; ks < 2; ++ks) {                                    \
            int cp = ((ks * 4 + lg) ^ (lr & 7)) * 8;                        \
            bf16x8 av[4], bv[4];                                            \
            _Pragma("unroll")                                               \
            for (int n = 0; n < 4; ++n)                                     \
                bv[n] = *(const bf16x8*)&sB[(wn * 64 + n * 16 + lr) * 64 + cp]; \
            _Pragma("unroll")                                               \
            for (int i = 0; i < 4; ++i)                                     \
                av[i] = *(const bf16x8*)&sA[(wm * 64 + i * 16 + lr) * 64 + cp]; \
            _Pragma("unroll")                                               \
            for (int i = 0; i < 4; ++i)                                     \
                _Pragma("unroll")                                           \
                for (int n = 0; n < 4; ++n)                                 \
                    acc[i][n] = __builtin_amdgcn_mfma_f32_16x16x32_bf16(    \
                        av[i], bv[n], acc[i][n], 0, 0, 0);                  \
        }                                                                   \
    }
#define BAR __builtin_amdgcn_s_barrier()

    STAGE(0, 0); STAGE(1, 1);                       // 12 outstanding
    asm volatile("s_waitcnt vmcnt(6)" ::: "memory"); BAR;
    for (int t = 0; t < 14; ++t) {
        COMPUTE(t & 1);
        BAR;                                        // done reading buf t&1
        STAGE(t & 1, t + 2);
        asm volatile("s_waitcnt vmcnt(6)" ::: "memory"); BAR;
    }
    COMPUTE(0);                                     // t = 14
    asm volatile("s_waitcnt vmcnt(0)" ::: "memory"); BAR;
    COMPUTE(1);                                     // t = 15
    __syncthreads();
#undef STAGE
#undef COMPUTE
#undef BAR

    // ---- epilogue ----
    unsigned short* wl = (unsigned short*)smem;
    float d1 = 0.f, d2 = 0.f;
    float cexp[4] = {0.f, 0.f, 0.f, 0.f};

    // stage W[i][j] tile: 256 rows x 128 cols = 64KB (rows 256B, swizzled)
#pragma unroll
    for (int c = 0; c < 8; ++c) {
        int q = w * 8 + c;                          // 0..63 (1KB issues)
        int sr = 4 * q + (lane >> 4);               // W row 0..255
        int gchunk = (lane & 15) ^ (sr & 7);        // source pre-swizzle
        gload16(Wg + (rowBase + sr) * (size_t)NB + colBase + gchunk * 8,
                smem + q * 1024);
    }
    __syncthreads();
#pragma unroll
    for (int m = 0; m < 4; ++m) {
        float rexp[4] = {0.f, 0.f, 0.f, 0.f};
#pragma unroll
        for (int n = 0; n < 4; ++n) {
            int jl = wn * 64 + n * 16 + lr;         // 0..127
#pragma unroll
            for (int r = 0; r < 4; ++r) {
                int rl = wm * 64 + m * 16 + lg * 4 + r;   // 0..255
                float sim = acc[m][n][r] * INV_T;
                float e = __expf(sim - INV_T);
                rexp[r] += e;
                cexp[n] += e;
                int ck = (jl >> 3) ^ (rl & 7);
                d1 += bf2f(wl[rl * 128 + ck * 8 + (jl & 7)]) * sim;
            }
        }
#pragma unroll
        for (int r = 0; r < 4; ++r) {
            float v = rexp[r];
            v += __shfl_xor(v, 1); v += __shfl_xor(v, 2);
            v += __shfl_xor(v, 4); v += __shfl_xor(v, 8);
            if (lr == 0)
                atomicAdd(&rowTgt[rowBase + wm * 64 + m * 16 + lg * 4 + r], v);
        }
    }
    __syncthreads();

    if (offdiag) {
#pragma unroll
        for (int n = 0; n < 4; ++n) {
            float v = cexp[n];
            v += __shfl_xor(v, 16); v += __shfl_xor(v, 32);
            if (lg == 0)
                atomicAdd(&colTgt[colBase + wn * 64 + n * 16 + lr], v);
        }
        // stage W[j][i] tile: 128 rows x 256 cols = 64KB (rows 512B, swizzled)
#pragma unroll
        for (int c = 0; c < 8; ++c) {
            int q = w * 8 + c;
            int sr = 2 * q + (lane >> 5);           // j row 0..127
            int gchunk = (lane & 31) ^ (sr & 7);
            gload16(Wg + (colBase + sr) * (size_t)NB + rowBase + gchunk * 8,
                    smem + q * 1024);
        }
        __syncthreads();
#pragma unroll
        for (int m = 0; m < 4; ++m) {
            int il0 = wm * 64 + m * 16 + lg * 4;    // 0..255 (step 4)
#pragma unroll
            for (int n = 0; n < 4; ++n) {
                int jl = wn * 64 + n * 16 + lr;     // 0..127
                int ck = (il0 >> 3) ^ (jl & 7);
                bf16x4 wv = *(const bf16x4*)&wl[jl * 256 + ck * 8 + (il0 & 7)];
#pragma unroll
                for (int r = 0; r < 4; ++r)
                    d2 += bf2f((unsigned short)wv[r]) * (acc[m][n][r] * INV_T);
            }
        }
    }

    if (mode == 0) {
        for (int off = 32; off; off >>= 1) {
            d1 += __shfl_xor(d1, off);
            d2 += __shfl_xor(d2, off);
        }
        if (lane == 0) {
            atomicAdd(&dots[0], d1);
            atomicAdd(&dots[1], d2);
        }
    } else {
        float dtot = d1 + (offdiag ? d2 : 0.f);
        for (int off = 32; off; off >>= 1) dtot += __shfl_xor(dtot, off);
        if (lane == 0) atomicAdd(&dots[1 + mode], dtot);
    }
}

// ---------------- kernel 4: finalize --------------------------------------
__global__ __launch_bounds__(256) void finalize_kernel(
        const float* __restrict__ rowsum1, const float* __restrict__ colsum1,
        const float* __restrict__ rowsum3, const float* __restrict__ rowsum4,
        const float* __restrict__ flag, const float* __restrict__ dots,
        float* __restrict__ out) {
    int tid = threadIdx.x;
    float l = 0.f;
    for (int i = tid; i < NB; i += 256) {
        if (flag[i] != 0.f) {
            l += 4.f * INV_T + logf(rowsum1[i]) + logf(colsum1[i]) +
                 logf(rowsum3[i]) + logf(rowsum4[i]);
        }
    }
    for (int off = 32; off; off >>= 1) l += __shfl_down(l, off);
    __shared__ float red[4];
    int lane = tid & 63, w = tid >> 6;
    if (lane == 0) red[w] = l;
    __syncthreads();
    if (tid == 0) {
        float L = red[0] + red[1] + red[2] + red[3];
        float dt = dots[0] + dots[1] + dots[2] + dots[3];
        out[0] = (L - dt) / (4.0f * (float)NB);
    }
}

extern "C" void kernel_launch(void* const* d_in, const int* in_sizes, int n_in,
                              void* d_out, int out_size, void* d_ws, size_t ws_size,
                              hipStream_t stream) {
    const float* M = (const float*)d_in[0];
    const float* P = (const float*)d_in[1];
    const int* labels = (const int*)d_in[2];
    const int* sm = (const int*)d_in[3];
    const int* sp = (const int*)d_in[4];
    const float* cs = (const float*)d_in[5];
    float* out = (float*)d_out;

    char* ws = (char*)d_ws;
    __hip_bfloat16* Mn = (__hip_bfloat16*)ws;                              // 8 MB
    __hip_bfloat16* Pn = (__hip_bfloat16*)(ws + (size_t)8 * 1024 * 1024);  // 8 MB
    unsigned short* W = (unsigned short*)(ws + (size_t)16 * 1024 * 1024);  // 32 MB
    char* p = ws + (size_t)48 * 1024 * 1024;
    int* code = (int*)p;        p += 16384;
    float* flag = (float*)p;    p += 16384;
    float* rowsum1 = (float*)p; p += 16384;
    float* colsum1 = (float*)p; p += 16384;
    float* rowsum3 = (float*)p; p += 16384;
    float* rowsum4 = (float*)p; p += 16384;
    float* dots = (float*)p;

    hipMemsetAsync(rowsum1, 0, 4 * 16384 + 256, stream);

    norm_kernel<<<2 * NB, 256, 0, stream>>>(M, P, Mn, Pn);
    key_kernel<<<NB / 256, 256, 0, stream>>>(labels, sm, sp, code);
    rowsumw_kernel<<<NB, 256, 0, stream>>>(cs, code, W, flag);

    mega_gemm<<<1056, 512, 0, stream>>>(Mn, Pn, W, rowsum1, colsum1,
                                        rowsum3, rowsum4, dots);

    finalize_kernel<<<1, 256, 0, stream>>>(rowsum1, colsum1, rowsum3, rowsum4,
                                           flag, dots, out);
}